// Round 2
// 986.872 us; speedup vs baseline: 1.0790x; 1.0790x over previous
//
#include <hip/hip_runtime.h>

// PhotonicNetworkGPU on MI355X — bf16 MFMA, 8-wave/block spill-free version.
// Per (b, w, m-half) block: field tile (256 s x 32 m x {re,im}) in LDS as bf16,
// TRANSPOSED: fldT[col][s], col = comp*32 + m_local, pitch 264 bf16.
// 512 threads = 8 waves; wave wv owns output rows wv*32..wv*32+31 (ONE 32x32
// row-tile -> acc[2] = 32 VGPRs, fp32 state sr/si = 32 VGPRs; the 4-wave
// version had 128 persistent regs at a 128-VGPR cap -> ~1 GB/dir scratch spill
// traffic, which dominated the runtime).
// conn is bf16 in d_ws (prep kernel), A-fragments read directly from global
// (L2-resident; streaming field reads/out writes are non-temporal so they
// don't evict it).

#define NB 32
#define NS 256
#define NW 64
#define NM 64
#define PLANE (NB * NS * NW * NM)
#define PITCH 264   // 256 + 8 bf16: 528 B col stride -> quad stride 33 (odd) -> conflict-free b128

typedef short bfrag __attribute__((ext_vector_type(8)));
typedef short bfx4  __attribute__((ext_vector_type(4)));
typedef float accv  __attribute__((ext_vector_type(16)));
typedef float fx4   __attribute__((ext_vector_type(4)));   // clang vec: OK for nontemporal builtins

__device__ __forceinline__ short f2bf(float x) {   // RNE truncate f32 -> bf16
    union { float f; unsigned u; } v; v.f = x;
    unsigned r = (v.u + 0x7fffu + ((v.u >> 16) & 1u)) >> 16;
    return (short)r;
}
__device__ __forceinline__ float bf2f(short s) {
    union { unsigned u; float f; } v; v.u = ((unsigned)(unsigned short)s) << 16;
    return v.f;
}

__global__ __launch_bounds__(256)
void conn_to_bf16(const float* __restrict__ c, short* __restrict__ o) {
    const int i = (blockIdx.x * 256 + threadIdx.x) * 4;   // 64 blocks cover 65536
    const float4 v = *reinterpret_cast<const float4*>(c + i);
    unsigned lo = (unsigned short)f2bf(v.x) | ((unsigned)(unsigned short)f2bf(v.y) << 16);
    unsigned hi = (unsigned short)f2bf(v.z) | ((unsigned)(unsigned short)f2bf(v.w) << 16);
    *reinterpret_cast<uint2*>(o + i) = make_uint2(lo, hi);
}

__global__ __launch_bounds__(512, 4)
void photonic_mfma(const float* __restrict__ fr, const float* __restrict__ fi,
                   const short* __restrict__ cb, const float* __restrict__ gain,
                   const float* __restrict__ bias, const float* __restrict__ ww,
                   const float* __restrict__ dshape, float* __restrict__ out)
{
    __shared__ __align__(16) short fldT[64 * PITCH];   // 33,792 B
    __shared__ float4 cons[NS];                        // (gain, bias, 0.95*ww, -)

    const int t    = threadIdx.x;
    const int bid  = blockIdx.x;
    const int b    = bid >> 7;
    const int w    = (bid >> 1) & 63;
    const int h    = bid & 1;

    const int wv      = t >> 6;        // 0..7
    const int lane    = t & 63;
    const int half    = lane >> 5;
    const int l31     = lane & 31;
    const int rowbase = wv * 32;       // one 32-row tile per wave

    // ---------------- stage field -> LDS (bf16, transposed) ----------------
    {
        const int q  = t & 7;          // m-quad
        const int r0 = t >> 3;         // s mod 64
        #pragma unroll
        for (int pass = 0; pass < 4; ++pass) {
            const int s = pass * 64 + r0;
            const int g = ((b * NS + s) * NW + w) * NM + h * 32 + q * 4;
            const fx4 re = __builtin_nontemporal_load(reinterpret_cast<const fx4*>(fr + g));
            const fx4 im = __builtin_nontemporal_load(reinterpret_cast<const fx4*>(fi + g));
            fldT[(q * 4 + 0) * PITCH + s] = f2bf(re.x);
            fldT[(q * 4 + 1) * PITCH + s] = f2bf(re.y);
            fldT[(q * 4 + 2) * PITCH + s] = f2bf(re.z);
            fldT[(q * 4 + 3) * PITCH + s] = f2bf(re.w);
            fldT[(32 + q * 4 + 0) * PITCH + s] = f2bf(im.x);
            fldT[(32 + q * 4 + 1) * PITCH + s] = f2bf(im.y);
            fldT[(32 + q * 4 + 2) * PITCH + s] = f2bf(im.z);
            fldT[(32 + q * 4 + 3) * PITCH + s] = f2bf(im.w);
        }
    }
    if (t < NS) cons[t] = make_float4(gain[t], bias[t], 0.95f * ww[t * NW + w], 0.0f);

    const float th  = 0.1f * dshape[w];
    const float cpr = cosf(th);
    const float cpi = sinf(th);

    __syncthreads();

    // ------------- fp32 register state for the lane's owned elements -------
    // ownership (C/D layout of 32x32 MFMA): s = rowbase + q*8 + 4*half + j, m = l31
    float sr[16], si[16];
    #pragma unroll
    for (int q = 0; q < 4; ++q) {
        const int srow = rowbase + q * 8 + 4 * half;
        const bfx4 r4 = *reinterpret_cast<const bfx4*>(&fldT[l31 * PITCH + srow]);
        const bfx4 i4 = *reinterpret_cast<const bfx4*>(&fldT[(32 + l31) * PITCH + srow]);
        #pragma unroll
        for (int j = 0; j < 4; ++j) {
            sr[q * 4 + j] = bf2f(r4[j]);
            si[q * 4 + j] = bf2f(i4[j]);
        }
    }

    const short* arow = cb + (rowbase + l31) * NS + half * 8;   // A rows (conn)
    const short* bre  = &fldT[l31 * PITCH + half * 8];          // B cols, re
    const short* bim  = &fldT[(32 + l31) * PITCH + half * 8];   // B cols, im

    for (int step = 0; step < 4; ++step) {
        if (step > 0) __syncthreads();   // prev epilogue writes -> visible

        accv ar, ai;
        #pragma unroll
        for (int r = 0; r < 16; ++r) { ar[r] = 0.0f; ai[r] = 0.0f; }

        #pragma unroll
        for (int k0 = 0; k0 < NS; k0 += 16) {
            const bfrag A  = *reinterpret_cast<const bfrag*>(arow + k0);
            const bfrag B0 = *reinterpret_cast<const bfrag*>(bre + k0);
            const bfrag B1 = *reinterpret_cast<const bfrag*>(bim + k0);
            ar = __builtin_amdgcn_mfma_f32_32x32x16_bf16(A, B0, ar, 0, 0, 0);
            ai = __builtin_amdgcn_mfma_f32_32x32x16_bf16(A, B1, ai, 0, 0, 0);
        }

        __syncthreads();   // everyone done reading fldT

        if (step < 3) {
            #pragma unroll
            for (int q = 0; q < 4; ++q) {
                const int srow = rowbase + q * 8 + 4 * half;
                unsigned short pr_[4], pi_[4];
                #pragma unroll
                for (int j = 0; j < 4; ++j) {
                    const int r = q * 4 + j;
                    const float4 cc = cons[srow + j];
                    float re = cc.x * (sr[r] + ar[r]) + cc.y;
                    float im = cc.x * (si[r] + ai[r]);
                    const float inv = 1.0f / (1.0f + 0.5f * (re * re + im * im));
                    re *= inv; im *= inv;
                    const float nr = (re * cpr - im * cpi) * cc.z;
                    const float ni = (re * cpi + im * cpr) * cc.z;
                    sr[r] = nr; si[r] = ni;
                    pr_[j] = (unsigned short)f2bf(nr);
                    pi_[j] = (unsigned short)f2bf(ni);
                }
                const uint2 pre = make_uint2(pr_[0] | ((unsigned)pr_[1] << 16),
                                             pr_[2] | ((unsigned)pr_[3] << 16));
                const uint2 pim = make_uint2(pi_[0] | ((unsigned)pi_[1] << 16),
                                             pi_[2] | ((unsigned)pi_[3] << 16));
                *reinterpret_cast<uint2*>(&fldT[l31 * PITCH + srow])        = pre;
                *reinterpret_cast<uint2*>(&fldT[(32 + l31) * PITCH + srow]) = pim;
            }
        } else {
            #pragma unroll
            for (int q = 0; q < 4; ++q) {
                const int srow = rowbase + q * 8 + 4 * half;
                #pragma unroll
                for (int j = 0; j < 4; ++j) {
                    const int r = q * 4 + j;
                    const float4 cc = cons[srow + j];
                    float re = cc.x * (sr[r] + ar[r]) + cc.y;
                    float im = cc.x * (si[r] + ai[r]);
                    const float inv = 1.0f / (1.0f + 0.5f * (re * re + im * im));
                    re *= inv; im *= inv;
                    const float nr = (re * cpr - im * cpi) * cc.z;
                    const float ni = (re * cpi + im * cpr) * cc.z;
                    const int idx = ((b * NS + srow + j) * NW + w) * NM + h * 32 + l31;
                    __builtin_nontemporal_store(nr, out + idx);          // coalesced: l31 fast dim
                    __builtin_nontemporal_store(ni, out + PLANE + idx);
                }
            }
        }
    }
}

extern "C" void kernel_launch(void* const* d_in, const int* in_sizes, int n_in,
                              void* d_out, int out_size, void* d_ws, size_t ws_size,
                              hipStream_t stream)
{
    const float* fr  = (const float*)d_in[0];
    const float* fi  = (const float*)d_in[1];
    const float* cn  = (const float*)d_in[2];
    const float* gn  = (const float*)d_in[3];
    const float* bs  = (const float*)d_in[4];
    const float* wwp = (const float*)d_in[5];
    const float* ds  = (const float*)d_in[6];
    float* out = (float*)d_out;
    short* cb  = (short*)d_ws;   // 65536 bf16 = 128 KiB

    hipLaunchKernelGGL(conn_to_bf16, dim3(64), dim3(256), 0, stream, cn, cb);
    hipLaunchKernelGGL(photonic_mfma, dim3(NB * NW * 2), dim3(512), 0, stream,
                       fr, fi, cb, gn, bs, wwp, ds, out);
}

// Round 3
// 660.811 us; speedup vs baseline: 1.6114x; 1.4934x over previous
//
#include <hip/hip_runtime.h>

// PhotonicNetworkGPU on MI355X — round 3: traffic-elimination version.
// Structure: grid = 64 w * 8 grp = 512 blocks of 1024 threads (16 waves).
// Each block processes 8 field tiles (b,h) for one w; conn (bf16, d_ws) is
// loaded into REGISTERS once per block (wave wv owns rows wv*16..wv*16+15,
// mfma_f32_16x16x32_bf16, A-frags = 8 x bfrag = 32 VGPRs) -- this cuts conn
// global request volume from 2.1 GB (per-step re-reads) to 64 MB.
// Field tile lives in LDS as bf16 transposed fldT[col][s], pitch 264.
// Next tile's field is prefetched into registers during compute (write-late).
// Output goes through an LDS f32 staging buffer and is stored as full-line
// nontemporal float4s (tests the ~1 GB write-amplification seen with scalar
// dword stores in rounds 0-2).

#define NB 32
#define NS 256
#define NW 64
#define NM 64
#define PLANE (NB * NS * NW * NM)
#define PITCH 264   // short pitch: 528 B col stride -> conflict-tolerable b128
#define PM 36       // float pitch for f32 output staging fb[s][m]
#define TILES 8

typedef short bfrag __attribute__((ext_vector_type(8)));
typedef short bfx4  __attribute__((ext_vector_type(4)));
typedef float accv4 __attribute__((ext_vector_type(4)));
typedef float fx4   __attribute__((ext_vector_type(4)));

__device__ __forceinline__ short f2bf(float x) {   // RNE f32 -> bf16
    union { float f; unsigned u; } v; v.f = x;
    unsigned r = (v.u + 0x7fffu + ((v.u >> 16) & 1u)) >> 16;
    return (short)r;
}
__device__ __forceinline__ float bf2f(short s) {
    union { unsigned u; float f; } v; v.u = ((unsigned)(unsigned short)s) << 16;
    return v.f;
}

__global__ __launch_bounds__(256)
void conn_to_bf16(const float* __restrict__ c, short* __restrict__ o) {
    const int i = (blockIdx.x * 256 + threadIdx.x) * 4;   // 64 blocks cover 65536
    const float4 v = *reinterpret_cast<const float4*>(c + i);
    unsigned lo = (unsigned short)f2bf(v.x) | ((unsigned)(unsigned short)f2bf(v.y) << 16);
    unsigned hi = (unsigned short)f2bf(v.z) | ((unsigned)(unsigned short)f2bf(v.w) << 16);
    *reinterpret_cast<uint2*>(o + i) = make_uint2(lo, hi);
}

__global__ __launch_bounds__(1024, 4)
void photonic_mfma(const float* __restrict__ fr, const float* __restrict__ fi,
                   const short* __restrict__ cb, const float* __restrict__ gain,
                   const float* __restrict__ bias, const float* __restrict__ ww,
                   const float* __restrict__ dshape, float* __restrict__ out)
{
    __shared__ __align__(16) float fb[NS * PM];   // 36,864 B; aliased as bf16 fldT
    __shared__ float4 cons[NS];                   // (gain, bias, 0.95*ww, -)
    short* const fldT = (short*)fb;

    const int t   = threadIdx.x;
    const int bid = blockIdx.x;
    const int w   = bid >> 3;          // 0..63
    const int grp = bid & 7;           // 0..7

    const int lane = t & 63;
    const int wv   = t >> 6;           // 0..15
    const int lo   = lane & 15;
    const int hi   = lane >> 4;        // 0..3
    const int rowb = wv * 16;          // wave's 16 output rows
    const int srow = rowb + hi * 4;    // C/D: row = (lane>>4)*4 + j, col = lane&15

    if (t < NS) cons[t] = make_float4(gain[t], bias[t], 0.95f * ww[t * NW + w], 0.0f);
    const float th  = 0.1f * dshape[w];
    const float cpr = cosf(th);
    const float cpi = sinf(th);

    // staging geometry (all 1024 threads)
    const int q  = t & 7;      // m-quad
    const int r0 = t >> 3;     // 0..127

    // ---- prefetch tile 0 fields into registers ----
    fx4 pre_re[2], pre_im[2];
    {
        const int td = grp * TILES;
        const int b = td >> 1, h = td & 1;
        #pragma unroll
        for (int pass = 0; pass < 2; ++pass) {
            const int s = pass * 128 + r0;
            const int g = ((b * NS + s) * NW + w) * NM + h * 32 + q * 4;
            pre_re[pass] = __builtin_nontemporal_load(reinterpret_cast<const fx4*>(fr + g));
            pre_im[pass] = __builtin_nontemporal_load(reinterpret_cast<const fx4*>(fi + g));
        }
    }

    // ---- conn rows -> registers, ONCE per block ----
    // A layout (16x16x32): row = lane&15, k = (lane>>4)*8 + e  (mirrors the
    // verified 32x32x16 mapping row=lane&31, k=(lane>>5)*8+e).
    bfrag Areg[8];
    {
        const short* ap = cb + (rowb + lo) * NS + hi * 8;
        #pragma unroll
        for (int kk = 0; kk < 8; ++kk)
            Areg[kk] = *reinterpret_cast<const bfrag*>(ap + kk * 32);
    }

    for (int tile = 0; tile < TILES; ++tile) {
        const int td = grp * TILES + tile;   // 0..63
        const int b  = td >> 1;
        const int h  = td & 1;

        __syncthreads();   // fb/fldT free (prev tile's store pass done)

        // ---- write prefetched fields -> LDS bf16 transposed ----
        #pragma unroll
        for (int pass = 0; pass < 2; ++pass) {
            const int s = pass * 128 + r0;
            const fx4 re = pre_re[pass];
            const fx4 im = pre_im[pass];
            fldT[(q * 4 + 0) * PITCH + s] = f2bf(re.x);
            fldT[(q * 4 + 1) * PITCH + s] = f2bf(re.y);
            fldT[(q * 4 + 2) * PITCH + s] = f2bf(re.z);
            fldT[(q * 4 + 3) * PITCH + s] = f2bf(re.w);
            fldT[(32 + q * 4 + 0) * PITCH + s] = f2bf(im.x);
            fldT[(32 + q * 4 + 1) * PITCH + s] = f2bf(im.y);
            fldT[(32 + q * 4 + 2) * PITCH + s] = f2bf(im.z);
            fldT[(32 + q * 4 + 3) * PITCH + s] = f2bf(im.w);
        }

        // ---- issue next tile's loads now; they complete during compute ----
        if (tile + 1 < TILES) {
            const int td2 = grp * TILES + tile + 1;
            const int b2 = td2 >> 1, h2 = td2 & 1;
            #pragma unroll
            for (int pass = 0; pass < 2; ++pass) {
                const int s = pass * 128 + r0;
                const int g = ((b2 * NS + s) * NW + w) * NM + h2 * 32 + q * 4;
                pre_re[pass] = __builtin_nontemporal_load(reinterpret_cast<const fx4*>(fr + g));
                pre_im[pass] = __builtin_nontemporal_load(reinterpret_cast<const fx4*>(fi + g));
            }
        }

        __syncthreads();

        // ---- fp32 register state: lane owns (s = srow+j, m = ct*16+lo) ----
        float sr0[4], si0[4], sr1[4], si1[4];
        {
            const bfx4 r4a = *reinterpret_cast<const bfx4*>(&fldT[lo * PITCH + srow]);
            const bfx4 i4a = *reinterpret_cast<const bfx4*>(&fldT[(32 + lo) * PITCH + srow]);
            const bfx4 r4b = *reinterpret_cast<const bfx4*>(&fldT[(16 + lo) * PITCH + srow]);
            const bfx4 i4b = *reinterpret_cast<const bfx4*>(&fldT[(48 + lo) * PITCH + srow]);
            #pragma unroll
            for (int j = 0; j < 4; ++j) {
                sr0[j] = bf2f(r4a[j]); si0[j] = bf2f(i4a[j]);
                sr1[j] = bf2f(r4b[j]); si1[j] = bf2f(i4b[j]);
            }
        }

        const short* bp0 = &fldT[lo * PITCH + hi * 8];          // B re, m-cols 0..15
        const short* bp1 = &fldT[(16 + lo) * PITCH + hi * 8];   // B re, m-cols 16..31
        const short* cp0 = &fldT[(32 + lo) * PITCH + hi * 8];   // B im, m-cols 0..15
        const short* cp1 = &fldT[(48 + lo) * PITCH + hi * 8];   // B im, m-cols 16..31

        for (int step = 0; step < 4; ++step) {
            if (step > 0) __syncthreads();   // prev epilogue LDS writes visible

            accv4 ar0, ar1, ai0, ai1;
            #pragma unroll
            for (int j = 0; j < 4; ++j) { ar0[j] = 0.0f; ar1[j] = 0.0f; ai0[j] = 0.0f; ai1[j] = 0.0f; }

            #pragma unroll
            for (int kk = 0; kk < 8; ++kk) {
                const bfrag B0 = *reinterpret_cast<const bfrag*>(bp0 + kk * 32);
                const bfrag B1 = *reinterpret_cast<const bfrag*>(bp1 + kk * 32);
                const bfrag C0 = *reinterpret_cast<const bfrag*>(cp0 + kk * 32);
                const bfrag C1 = *reinterpret_cast<const bfrag*>(cp1 + kk * 32);
                ar0 = __builtin_amdgcn_mfma_f32_16x16x32_bf16(Areg[kk], B0, ar0, 0, 0, 0);
                ar1 = __builtin_amdgcn_mfma_f32_16x16x32_bf16(Areg[kk], B1, ar1, 0, 0, 0);
                ai0 = __builtin_amdgcn_mfma_f32_16x16x32_bf16(Areg[kk], C0, ai0, 0, 0, 0);
                ai1 = __builtin_amdgcn_mfma_f32_16x16x32_bf16(Areg[kk], C1, ai1, 0, 0, 0);
            }

            __syncthreads();   // all lanes done reading fldT

            if (step < 3) {
                unsigned short pr_[4], pi_[4];
                #pragma unroll
                for (int j = 0; j < 4; ++j) {
                    const float4 cc = cons[srow + j];
                    float re = cc.x * (sr0[j] + ar0[j]) + cc.y;
                    float im = cc.x * (si0[j] + ai0[j]);
                    const float inv = 1.0f / (1.0f + 0.5f * (re * re + im * im));
                    re *= inv; im *= inv;
                    const float nr = (re * cpr - im * cpi) * cc.z;
                    const float ni = (re * cpi + im * cpr) * cc.z;
                    sr0[j] = nr; si0[j] = ni;
                    pr_[j] = (unsigned short)f2bf(nr);
                    pi_[j] = (unsigned short)f2bf(ni);
                }
                *reinterpret_cast<uint2*>(&fldT[lo * PITCH + srow]) =
                    make_uint2(pr_[0] | ((unsigned)pr_[1] << 16), pr_[2] | ((unsigned)pr_[3] << 16));
                *reinterpret_cast<uint2*>(&fldT[(32 + lo) * PITCH + srow]) =
                    make_uint2(pi_[0] | ((unsigned)pi_[1] << 16), pi_[2] | ((unsigned)pi_[3] << 16));
                #pragma unroll
                for (int j = 0; j < 4; ++j) {
                    const float4 cc = cons[srow + j];
                    float re = cc.x * (sr1[j] + ar1[j]) + cc.y;
                    float im = cc.x * (si1[j] + ai1[j]);
                    const float inv = 1.0f / (1.0f + 0.5f * (re * re + im * im));
                    re *= inv; im *= inv;
                    const float nr = (re * cpr - im * cpi) * cc.z;
                    const float ni = (re * cpi + im * cpr) * cc.z;
                    sr1[j] = nr; si1[j] = ni;
                    pr_[j] = (unsigned short)f2bf(nr);
                    pi_[j] = (unsigned short)f2bf(ni);
                }
                *reinterpret_cast<uint2*>(&fldT[(16 + lo) * PITCH + srow]) =
                    make_uint2(pr_[0] | ((unsigned)pr_[1] << 16), pr_[2] | ((unsigned)pr_[3] << 16));
                *reinterpret_cast<uint2*>(&fldT[(48 + lo) * PITCH + srow]) =
                    make_uint2(pi_[0] | ((unsigned)pi_[1] << 16), pi_[2] | ((unsigned)pi_[3] << 16));
            } else {
                // final step: compute, then LDS-stage + full-line float4 stores
                #pragma unroll
                for (int j = 0; j < 4; ++j) {
                    const float4 cc = cons[srow + j];
                    {
                        float re = cc.x * (sr0[j] + ar0[j]) + cc.y;
                        float im = cc.x * (si0[j] + ai0[j]);
                        const float inv = 1.0f / (1.0f + 0.5f * (re * re + im * im));
                        re *= inv; im *= inv;
                        sr0[j] = (re * cpr - im * cpi) * cc.z;
                        si0[j] = (re * cpi + im * cpr) * cc.z;
                    }
                    {
                        float re = cc.x * (sr1[j] + ar1[j]) + cc.y;
                        float im = cc.x * (si1[j] + ai1[j]);
                        const float inv = 1.0f / (1.0f + 0.5f * (re * re + im * im));
                        re *= inv; im *= inv;
                        sr1[j] = (re * cpr - im * cpi) * cc.z;
                        si1[j] = (re * cpi + im * cpr) * cc.z;
                    }
                }
                // re plane
                #pragma unroll
                for (int j = 0; j < 4; ++j) {
                    fb[(srow + j) * PM + lo]      = sr0[j];
                    fb[(srow + j) * PM + 16 + lo] = sr1[j];
                }
                __syncthreads();
                #pragma unroll
                for (int it = 0; it < 2; ++it) {
                    const int slot = it * 1024 + t;
                    const int s  = slot >> 3;
                    const int mq = slot & 7;
                    const fx4 v = *reinterpret_cast<const fx4*>(&fb[s * PM + mq * 4]);
                    const int gi = ((b * NS + s) * NW + w) * NM + h * 32 + mq * 4;
                    __builtin_nontemporal_store(v, reinterpret_cast<fx4*>(out + gi));
                }
                __syncthreads();
                // im plane
                #pragma unroll
                for (int j = 0; j < 4; ++j) {
                    fb[(srow + j) * PM + lo]      = si0[j];
                    fb[(srow + j) * PM + 16 + lo] = si1[j];
                }
                __syncthreads();
                #pragma unroll
                for (int it = 0; it < 2; ++it) {
                    const int slot = it * 1024 + t;
                    const int s  = slot >> 3;
                    const int mq = slot & 7;
                    const fx4 v = *reinterpret_cast<const fx4*>(&fb[s * PM + mq * 4]);
                    const int gi = ((b * NS + s) * NW + w) * NM + h * 32 + mq * 4;
                    __builtin_nontemporal_store(v, reinterpret_cast<fx4*>(out + PLANE + gi));
                }
            }
        }
    }
}

extern "C" void kernel_launch(void* const* d_in, const int* in_sizes, int n_in,
                              void* d_out, int out_size, void* d_ws, size_t ws_size,
                              hipStream_t stream)
{
    const float* fr  = (const float*)d_in[0];
    const float* fi  = (const float*)d_in[1];
    const float* cn  = (const float*)d_in[2];
    const float* gn  = (const float*)d_in[3];
    const float* bs  = (const float*)d_in[4];
    const float* wwp = (const float*)d_in[5];
    const float* ds  = (const float*)d_in[6];
    float* out = (float*)d_out;
    short* cb  = (short*)d_ws;   // 65536 bf16 = 128 KiB

    hipLaunchKernelGGL(conn_to_bf16, dim3(64), dim3(256), 0, stream, cn, cb);
    hipLaunchKernelGGL(photonic_mfma, dim3(NW * 8), dim3(1024), 0, stream,
                       fr, fi, cb, gn, bs, wwp, ds, out);
}